// Round 1
// baseline (1862.761 us; speedup 1.0000x reference)
//
#include <hip/hip_runtime.h>
#include <math.h>

#define BB 16
#define NN 1024
#define KK 20
#define KTOT (256*1024)

// ---------------- transpose x (B,N,3) -> h (B,3,N) ----------------
__global__ void transpose_h(const float* __restrict__ x, float* __restrict__ h) {
    int t = blockIdx.x * 256 + threadIdx.x;
    if (t >= BB * NN) return;
    int b = t >> 10, n = t & 1023;
    const float* xp = x + (size_t)t * 3;
    float* hp = h + (size_t)b * 3 * NN + n;
    hp[0]      = xp[0];
    hp[NN]     = xp[1];
    hp[2 * NN] = xp[2];
}

// ---------------- xx[b][n] = sum_c x^2 ----------------
__global__ void xx_kernel(const float* __restrict__ x, float* __restrict__ xx, int C) {
    int t = blockIdx.x * 256 + threadIdx.x;
    if (t >= BB * NN) return;
    int b = t >> 10, n = t & 1023;
    const float* xp = x + (size_t)b * C * NN + n;
    float s = 0.f;
    for (int c = 0; c < C; ++c) { float vv = xp[(size_t)c * NN]; s = fmaf(vv, vv, s); }
    xx[t] = s;
}

// ---------------- neg sq dist matrix: G[b][i][j] = 2*dot - xx_i - xx_j ----------------
__global__ __launch_bounds__(256) void dist_kernel(const float* __restrict__ x,
                                                   const float* __restrict__ xx,
                                                   float* __restrict__ G, int C) {
    __shared__ float As[16][64];
    __shared__ float Bs[16][64];
    int b = blockIdx.z;
    int i0 = blockIdx.y * 64, j0 = blockIdx.x * 64;
    int t = threadIdx.x;
    int tx = t & 15, ty = t >> 4;   // tx -> j sub-tile (fast, for coalesced store), ty -> i
    float acc[4][4] = {{0.f}};
    const float* xb = x + (size_t)b * C * NN;
    for (int kc = 0; kc < C; kc += 16) {
        for (int e = t; e < 1024; e += 256) {
            int r = e >> 6, cc = e & 63;
            float av = 0.f, bv = 0.f;
            if (kc + r < C) {
                av = xb[(size_t)(kc + r) * NN + i0 + cc];
                bv = xb[(size_t)(kc + r) * NN + j0 + cc];
            }
            As[r][cc] = av;
            Bs[r][cc] = bv;
        }
        __syncthreads();
#pragma unroll
        for (int k = 0; k < 16; ++k) {
            float4 a  = *(const float4*)&As[k][ty * 4];
            float4 b4 = *(const float4*)&Bs[k][tx * 4];
            acc[0][0] += a.x * b4.x; acc[0][1] += a.x * b4.y; acc[0][2] += a.x * b4.z; acc[0][3] += a.x * b4.w;
            acc[1][0] += a.y * b4.x; acc[1][1] += a.y * b4.y; acc[1][2] += a.y * b4.z; acc[1][3] += a.y * b4.w;
            acc[2][0] += a.z * b4.x; acc[2][1] += a.z * b4.y; acc[2][2] += a.z * b4.z; acc[2][3] += a.z * b4.w;
            acc[3][0] += a.w * b4.x; acc[3][1] += a.w * b4.y; acc[3][2] += a.w * b4.z; acc[3][3] += a.w * b4.w;
        }
        __syncthreads();
    }
    float xi[4], xj[4];
#pragma unroll
    for (int ii = 0; ii < 4; ++ii) xi[ii] = xx[b * NN + i0 + ty * 4 + ii];
#pragma unroll
    for (int jj = 0; jj < 4; ++jj) xj[jj] = xx[b * NN + j0 + tx * 4 + jj];
    float* gp = G + ((size_t)b << 20);
#pragma unroll
    for (int ii = 0; ii < 4; ++ii) {
        float4 o;
        o.x = 2.f * acc[ii][0] - xi[ii] - xj[0];
        o.y = 2.f * acc[ii][1] - xi[ii] - xj[1];
        o.z = 2.f * acc[ii][2] - xi[ii] - xj[2];
        o.w = 2.f * acc[ii][3] - xi[ii] - xj[3];
        *(float4*)(gp + (size_t)(i0 + ty * 4 + ii) * NN + j0 + tx * 4) = o;
    }
}

// ---------------- top-20 per row (one wave per row) ----------------
__global__ __launch_bounds__(256) void topk_kernel(const float* __restrict__ G,
                                                   int* __restrict__ idxout) {
    int lane = threadIdx.x & 63, wv = threadIdx.x >> 6;
    int row = blockIdx.x * 4 + wv;                 // 0..16383
    int b = row >> 10, n = row & 1023;
    const float* g = G + ((size_t)b << 20) + ((size_t)n << 10);
    float d[16];
#pragma unroll
    for (int i = 0; i < 16; ++i) d[i] = g[i * 64 + lane];
    int* op = idxout + (size_t)row * KK;
    for (int s = 0; s < KK; ++s) {
        float bv = d[0]; int bi = 0;
#pragma unroll
        for (int i = 1; i < 16; ++i) { if (d[i] > bv) { bv = d[i]; bi = i; } }
        int bm = bi * 64 + lane;
#pragma unroll
        for (int o = 32; o; o >>= 1) {
            float ov = __shfl_xor(bv, o, 64);
            int   om = __shfl_xor(bm, o, 64);
            if (ov > bv || (ov == bv && om < bm)) { bv = ov; bm = om; }
        }
        if (lane == 0) op[s] = bm;
        if ((bm & 63) == lane) {
            int wr = bm >> 6;
#pragma unroll
            for (int i = 0; i < 16; ++i) { if (i == wr) d[i] = -INFINITY; }
        }
    }
}

// ---------------- u = W1 @ x ; v = (W2-W1) @ x ----------------
__global__ __launch_bounds__(256) void transform_kernel(const float* __restrict__ x,
                                                        const float* __restrict__ W,
                                                        float* __restrict__ u, float* __restrict__ v,
                                                        int C, int O) {
    __shared__ float xs[128 * 64];
    int b = blockIdx.y, n0 = blockIdx.x * 64;
    int t = threadIdx.x;
    int nl = t & 63, oq = t >> 6;
    const float* xb = x + (size_t)b * C * NN;
    for (int e = t; e < C * 64; e += 256) {
        int c = e >> 6, ni = e & 63;
        xs[e] = xb[(size_t)c * NN + n0 + ni];
    }
    __syncthreads();
    for (int o = oq; o < O; o += 4) {
        const float* w1 = W + (size_t)o * 2 * C;
        float au = 0.f, av = 0.f;
        for (int c = 0; c < C; ++c) {
            float xv = xs[c * 64 + nl];
            au = fmaf(w1[c], xv, au);
            av = fmaf(w1[C + c] - w1[c], xv, av);
        }
        size_t oi = ((size_t)(b * O + o)) * NN + n0 + nl;
        u[oi] = au;
        v[oi] = av;
    }
}

// ---------------- per-channel sum / sumsq of y = u[idx] + v ----------------
__global__ __launch_bounds__(256) void stats_kernel(const float* __restrict__ u,
                                                    const float* __restrict__ v,
                                                    const int* __restrict__ idx,
                                                    double* __restrict__ sums,
                                                    double* __restrict__ sumsq, int O) {
    __shared__ float us[NN];
    __shared__ double red[8];
    int o = blockIdx.x, b = blockIdx.y;
    const float* up = u + ((size_t)(b * O + o)) * NN;
    for (int e = threadIdx.x; e < NN; e += 256) us[e] = up[e];
    __syncthreads();
    const float* vp = v + ((size_t)(b * O + o)) * NN;
    const int* ip = idx + (size_t)b * NN * KK;
    float s = 0.f, s2 = 0.f;
    for (int n = threadIdx.x; n < NN; n += 256) {
        float vv = vp[n];
        const int* q = ip + n * KK;
#pragma unroll
        for (int j = 0; j < KK; ++j) {
            float val = us[q[j]] + vv;
            s += val;
            s2 = fmaf(val, val, s2);
        }
    }
    double ds = s, ds2 = s2;
#pragma unroll
    for (int ofs = 32; ofs; ofs >>= 1) {
        ds  += __shfl_xor(ds, ofs, 64);
        ds2 += __shfl_xor(ds2, ofs, 64);
    }
    int lane = threadIdx.x & 63, wv = threadIdx.x >> 6;
    if (lane == 0) { red[wv] = ds; red[4 + wv] = ds2; }
    __syncthreads();
    if (threadIdx.x == 0) {
        double a  = red[0] + red[1] + red[2] + red[3];
        double a2 = red[4] + red[5] + red[6] + red[7];
        atomicAdd(&sums[o], a);
        atomicAdd(&sumsq[o], a2);
    }
}

// ---------------- bn + lrelu + max over neighbors ----------------
__global__ __launch_bounds__(256) void outmax_kernel(const float* __restrict__ u,
                                                     const float* __restrict__ v,
                                                     const int* __restrict__ idx,
                                                     const double* __restrict__ sums,
                                                     const double* __restrict__ sumsq,
                                                     const float* __restrict__ gam,
                                                     const float* __restrict__ bet,
                                                     float* __restrict__ xout, int O) {
    __shared__ float us[NN];
    int o = blockIdx.x, b = blockIdx.y;
    const float* up = u + ((size_t)(b * O + o)) * NN;
    for (int e = threadIdx.x; e < NN; e += 256) us[e] = up[e];
    __syncthreads();
    const double cntd = (double)BB * NN * KK;
    double mean = sums[o] / cntd;
    double var  = sumsq[o] / cntd - mean * mean;
    double inv  = 1.0 / sqrt(var + 1e-5);
    float sc = (float)((double)gam[o] * inv);
    float bi = (float)((double)bet[o] - mean * (double)gam[o] * inv);
    const float* vp = v + ((size_t)(b * O + o)) * NN;
    const int* ip = idx + (size_t)b * NN * KK;
    for (int n = threadIdx.x; n < NN; n += 256) {
        float vv = vp[n];
        const int* q = ip + n * KK;
        float m = -1e30f;
#pragma unroll
        for (int j = 0; j < KK; ++j) {
            float val = us[q[j]] + vv;
            float yh = val * sc + bi;
            float z = fmaxf(yh, 0.2f * yh);
            m = fmaxf(m, z);
        }
        xout[((size_t)(b * O + o)) * NN + n] = m;
    }
}

// ---------------- fc1 split-K partial: coalesced on the 512MB weight stream ----------------
__global__ __launch_bounds__(256) void fc1_partial(const float* __restrict__ x4,
                                                   const float* __restrict__ W,
                                                   float* __restrict__ part) {
    int lane = threadIdx.x & 63;
    int wv = threadIdx.x >> 6;
    int kc = blockIdx.x;                  // 0..15
    int mb = blockIdx.y * 16 + wv * 4;    // 4 m rows per wave
    int kbase = kc * (KTOT / 16);         // 16384 k per block
    float acc[4][16];
#pragma unroll
    for (int i = 0; i < 4; ++i)
#pragma unroll
        for (int j = 0; j < 16; ++j) acc[i][j] = 0.f;
    for (int step = 0; step < 64; ++step) {
        int k = kbase + step * 256 + lane * 4;
        float4 w0 = *(const float4*)(W + (size_t)(mb + 0) * KTOT + k);
        float4 w1 = *(const float4*)(W + (size_t)(mb + 1) * KTOT + k);
        float4 w2 = *(const float4*)(W + (size_t)(mb + 2) * KTOT + k);
        float4 w3 = *(const float4*)(W + (size_t)(mb + 3) * KTOT + k);
#pragma unroll
        for (int b = 0; b < 16; ++b) {
            float4 f = *(const float4*)(x4 + (size_t)b * KTOT + k);
            acc[0][b] += w0.x * f.x + w0.y * f.y + w0.z * f.z + w0.w * f.w;
            acc[1][b] += w1.x * f.x + w1.y * f.y + w1.z * f.z + w1.w * f.w;
            acc[2][b] += w2.x * f.x + w2.y * f.y + w2.z * f.z + w2.w * f.w;
            acc[3][b] += w3.x * f.x + w3.y * f.y + w3.z * f.z + w3.w * f.w;
        }
    }
#pragma unroll
    for (int i = 0; i < 4; ++i)
#pragma unroll
        for (int b = 0; b < 16; ++b) {
            float s = acc[i][b];
#pragma unroll
            for (int o = 32; o; o >>= 1) s += __shfl_xor(s, o, 64);
            if (lane == 0) part[((size_t)kc * 512 + mb + i) * 16 + b] = s;
        }
}

__global__ void fc1_reduce(const float* __restrict__ part, const float* __restrict__ bias,
                           float* __restrict__ x5) {
    int t = blockIdx.x * 256 + threadIdx.x;   // 0..8191
    int m = t & 511, b = t >> 9;
    float s = bias[m];
    for (int kc = 0; kc < 16; ++kc) s += part[((size_t)kc * 512 + m) * 16 + b];
    x5[b * 512 + m] = fmaxf(s, 0.f);
}

__global__ void fc2_kernel(const float* __restrict__ x5, const float* __restrict__ W,
                           const float* __restrict__ bias, float* __restrict__ x6) {
    int t = blockIdx.x * 256 + threadIdx.x;
    int m = t & 511, b = t >> 9;
    const float* wr = W + (size_t)m * 512;
    const float* xr = x5 + b * 512;
    float s = bias[m];
    for (int q = 0; q < 512; q += 4) {
        float4 w = *(const float4*)(wr + q);
        float4 xv = *(const float4*)(xr + q);
        s += w.x * xv.x + w.y * xv.y + w.z * xv.z + w.w * xv.w;
    }
    x6[b * 512 + m] = fmaxf(s, 0.f);
}

__global__ void fc3_kernel(const float* __restrict__ x6, const float* __restrict__ W,
                           const float* __restrict__ bias, float* __restrict__ out) {
    int t = threadIdx.x;
    if (t >= 32) return;
    int b = t >> 1, c = t & 1;
    const float* wr = W + (size_t)c * 512;
    const float* xr = x6 + b * 512;
    float s = bias[c];
    for (int q = 0; q < 512; ++q) s += wr[q] * xr[q];
    out[b * 2 + c] = s;
}

extern "C" void kernel_launch(void* const* d_in, const int* in_sizes, int n_in,
                              void* d_out, int out_size, void* d_ws, size_t ws_size,
                              hipStream_t stream) {
    (void)in_sizes; (void)n_in; (void)out_size; (void)ws_size;
    const float* x = (const float*)d_in[0];
    const float* w_conv[4] = {(const float*)d_in[1], (const float*)d_in[4],
                              (const float*)d_in[7], (const float*)d_in[10]};
    const float* g_bn[4] = {(const float*)d_in[2], (const float*)d_in[5],
                            (const float*)d_in[8], (const float*)d_in[11]};
    const float* b_bn[4] = {(const float*)d_in[3], (const float*)d_in[6],
                            (const float*)d_in[9], (const float*)d_in[12]};
    const float* fc1w = (const float*)d_in[13];
    const float* fc1b = (const float*)d_in[14];
    const float* fc2w = (const float*)d_in[15];
    const float* fc2b = (const float*)d_in[16];
    const float* fc3w = (const float*)d_in[17];
    const float* fc3b = (const float*)d_in[18];
    float* out = (float*)d_out;

    char* wsb = (char*)d_ws;
    size_t off = 0;
    auto alloc = [&](size_t bytes) -> void* {
        void* p = wsb + off;
        off = (off + bytes + 255) & ~(size_t)255;
        return p;
    };
    float* h    = (float*)alloc((size_t)BB * 3 * NN * 4);
    float* x1   = (float*)alloc((size_t)BB * 64 * NN * 4);
    float* x2   = (float*)alloc((size_t)BB * 64 * NN * 4);
    float* x3   = (float*)alloc((size_t)BB * 128 * NN * 4);
    float* x4   = (float*)alloc((size_t)BB * 256 * NN * 4);
    int*   idxb = (int*)alloc((size_t)BB * NN * KK * 4);
    float* xxb  = (float*)alloc((size_t)BB * NN * 4);
    float* G    = (float*)alloc((size_t)BB * NN * NN * 4);   // reused as u|v after topk
    double* sums  = (double*)alloc(256 * 8);
    double* sumsq = (double*)alloc(256 * 8);
    float* part = (float*)alloc((size_t)16 * 512 * 16 * 4);
    float* x5   = (float*)alloc((size_t)BB * 512 * 4);
    float* x6   = (float*)alloc((size_t)BB * 512 * 4);
    float* u = G;
    float* v = G + (size_t)BB * 256 * NN;

    transpose_h<<<64, 256, 0, stream>>>(x, h);

    struct LayerCfg { const float* xin; int C; int O; float* xout; };
    LayerCfg L[4] = {
        {h, 3, 64, x1}, {x1, 64, 64, x2}, {x2, 64, 128, x3}, {x3, 128, 256, x4}
    };
    for (int l = 0; l < 4; ++l) {
        const float* xin = L[l].xin;
        int C = L[l].C, O = L[l].O;
        float* xout = L[l].xout;
        xx_kernel<<<64, 256, 0, stream>>>(xin, xxb, C);
        dist_kernel<<<dim3(16, 16, BB), 256, 0, stream>>>(xin, xxb, G, C);
        topk_kernel<<<4096, 256, 0, stream>>>(G, idxb);
        transform_kernel<<<dim3(16, BB), 256, 0, stream>>>(xin, w_conv[l], u, v, C, O);
        hipMemsetAsync(sums, 0, 256 * 8, stream);
        hipMemsetAsync(sumsq, 0, 256 * 8, stream);
        stats_kernel<<<dim3(O, BB), 256, 0, stream>>>(u, v, idxb, sums, sumsq, O);
        outmax_kernel<<<dim3(O, BB), 256, 0, stream>>>(u, v, idxb, sums, sumsq,
                                                       g_bn[l], b_bn[l], xout, O);
    }

    fc1_partial<<<dim3(16, 32), 256, 0, stream>>>(x4, fc1w, part);
    fc1_reduce<<<32, 256, 0, stream>>>(part, fc1b, x5);
    fc2_kernel<<<32, 256, 0, stream>>>(x5, fc2w, fc2b, x6);
    fc3_kernel<<<1, 64, 0, stream>>>(x6, fc3w, fc3b, out);
}

// Round 2
// 1468.087 us; speedup vs baseline: 1.2688x; 1.2688x over previous
//
#include <hip/hip_runtime.h>
#include <math.h>

#define BB 16
#define NN 1024
#define KK 20
#define MM (BB*NN)          // 16384
#define KTOT (256*1024)
#define SPLIT 64
#define RCH 8

// ---------------- transpose x (B,N,3) -> h [c][b][n] ----------------
__global__ void transpose_h(const float* __restrict__ x, float* __restrict__ h) {
    int t = blockIdx.x * 256 + threadIdx.x;
    if (t >= MM) return;
    const float* xp = x + (size_t)t * 3;
    h[t]            = xp[0];
    h[MM + t]       = xp[1];
    h[2 * MM + t]   = xp[2];
}

// ---------------- xx[m] = sum_c F[c][m]^2 ----------------
__global__ void xx_kernel(const float* __restrict__ F, float* __restrict__ xx, int C) {
    int t = blockIdx.x * 256 + threadIdx.x;
    if (t >= MM) return;
    float s = 0.f;
    for (int c = 0; c < C; ++c) { float vv = F[(size_t)c * MM + t]; s = fmaf(vv, vv, s); }
    xx[t] = s;
}

// ---------------- G[b][i][j] = 2*dot - xx_i - xx_j  (F channel-major) ----------------
__global__ __launch_bounds__(256) void dist_kernel(const float* __restrict__ F,
                                                   const float* __restrict__ xx,
                                                   float* __restrict__ G, int C) {
    __shared__ float As[16][64];
    __shared__ float Bs[16][64];
    int b = blockIdx.z;
    int i0 = blockIdx.y * 64, j0 = blockIdx.x * 64;
    int t = threadIdx.x;
    int tx = t & 15, ty = t >> 4;
    float acc[4][4] = {{0.f}};
    for (int kc = 0; kc < C; kc += 16) {
        for (int e = t; e < 1024; e += 256) {
            int r = e >> 6, cc = e & 63;
            float av = 0.f, bv = 0.f;
            if (kc + r < C) {
                av = F[(size_t)(kc + r) * MM + b * NN + i0 + cc];
                bv = F[(size_t)(kc + r) * MM + b * NN + j0 + cc];
            }
            As[r][cc] = av;
            Bs[r][cc] = bv;
        }
        __syncthreads();
#pragma unroll
        for (int k = 0; k < 16; ++k) {
            float4 a  = *(const float4*)&As[k][ty * 4];
            float4 b4 = *(const float4*)&Bs[k][tx * 4];
            acc[0][0] += a.x * b4.x; acc[0][1] += a.x * b4.y; acc[0][2] += a.x * b4.z; acc[0][3] += a.x * b4.w;
            acc[1][0] += a.y * b4.x; acc[1][1] += a.y * b4.y; acc[1][2] += a.y * b4.z; acc[1][3] += a.y * b4.w;
            acc[2][0] += a.z * b4.x; acc[2][1] += a.z * b4.y; acc[2][2] += a.z * b4.z; acc[2][3] += a.z * b4.w;
            acc[3][0] += a.w * b4.x; acc[3][1] += a.w * b4.y; acc[3][2] += a.w * b4.z; acc[3][3] += a.w * b4.w;
        }
        __syncthreads();
    }
    float xi[4], xj[4];
#pragma unroll
    for (int ii = 0; ii < 4; ++ii) xi[ii] = xx[b * NN + i0 + ty * 4 + ii];
#pragma unroll
    for (int jj = 0; jj < 4; ++jj) xj[jj] = xx[b * NN + j0 + tx * 4 + jj];
    float* gp = G + ((size_t)b << 20);
#pragma unroll
    for (int ii = 0; ii < 4; ++ii) {
        float4 o;
        o.x = 2.f * acc[ii][0] - xi[ii] - xj[0];
        o.y = 2.f * acc[ii][1] - xi[ii] - xj[1];
        o.z = 2.f * acc[ii][2] - xi[ii] - xj[2];
        o.w = 2.f * acc[ii][3] - xi[ii] - xj[3];
        *(float4*)(gp + (size_t)(i0 + ty * 4 + ii) * NN + j0 + tx * 4) = o;
    }
}

// ---------------- top-20 per row, cached local max ----------------
__global__ __launch_bounds__(256) void topk_kernel(const float* __restrict__ G,
                                                   int* __restrict__ idxout) {
    int lane = threadIdx.x & 63, wv = threadIdx.x >> 6;
    int row = blockIdx.x * 4 + wv;
    int b = row >> 10, n = row & 1023;
    const float* g = G + ((size_t)b << 20) + ((size_t)n << 10);
    float d[16];
#pragma unroll
    for (int i = 0; i < 16; ++i) d[i] = g[i * 64 + lane];
    float lv = d[0]; int li = 0;
#pragma unroll
    for (int i = 1; i < 16; ++i) { if (d[i] > lv) { lv = d[i]; li = i; } }
    int* op = idxout + (size_t)row * KK;
    for (int s = 0; s < KK; ++s) {
        float bv = lv; int bm = li * 64 + lane;
#pragma unroll
        for (int o = 32; o; o >>= 1) {
            float ov = __shfl_xor(bv, o, 64);
            int   om = __shfl_xor(bm, o, 64);
            if (ov > bv || (ov == bv && om < bm)) { bv = ov; bm = om; }
        }
        if (lane == 0) op[s] = bm;
        if ((bm & 63) == lane) {
            int wr = bm >> 6;
#pragma unroll
            for (int i = 0; i < 16; ++i) { if (i == wr) d[i] = -INFINITY; }
            lv = d[0]; li = 0;
#pragma unroll
            for (int i = 1; i < 16; ++i) { if (d[i] > lv) { lv = d[i]; li = i; } }
        }
    }
}

// ---------------- WdT[c][r] = r<O ? W1 : W2-W1 ; also zero stats ----------------
__global__ void wprep(const float* __restrict__ W, float* __restrict__ WdT,
                      double* __restrict__ sums, double* __restrict__ sumsq,
                      int C, int O) {
    if (blockIdx.x == 0) { sums[threadIdx.x] = 0.0; sumsq[threadIdx.x] = 0.0; }
    int t = blockIdx.x * 256 + threadIdx.x;
    int R2 = 2 * O;
    if (t >= R2 * C) return;
    int c = t / R2, r = t % R2;
    float val;
    if (r < O) val = W[(size_t)r * 2 * C + c];
    else {
        const float* wr = W + (size_t)(r - O) * 2 * C;
        val = wr[C + c] - wr[c];
    }
    WdT[(size_t)c * R2 + r] = val;
}

// ---------------- Y[r][m] = sum_c WdT[c][r] * F[c][m] ----------------
__global__ __launch_bounds__(256) void gemm_uv(const float* __restrict__ WdT,
                                               const float* __restrict__ F,
                                               float* __restrict__ Y, int C, int R2) {
    __shared__ float As[16][64];
    __shared__ float Bs[16][64];
    int r0 = blockIdx.y * 64, m0 = blockIdx.x * 64;
    int t = threadIdx.x;
    int tx = t & 15, ty = t >> 4;
    float acc[4][4] = {{0.f}};
    for (int kc = 0; kc < C; kc += 16) {
        for (int e = t; e < 1024; e += 256) {
            int r = e >> 6, cc = e & 63;
            float av = 0.f, bv = 0.f;
            if (kc + r < C) {
                av = WdT[(size_t)(kc + r) * R2 + r0 + cc];
                bv = F[(size_t)(kc + r) * MM + m0 + cc];
            }
            As[r][cc] = av;
            Bs[r][cc] = bv;
        }
        __syncthreads();
#pragma unroll
        for (int k = 0; k < 16; ++k) {
            float4 a  = *(const float4*)&As[k][ty * 4];
            float4 b4 = *(const float4*)&Bs[k][tx * 4];
            acc[0][0] += a.x * b4.x; acc[0][1] += a.x * b4.y; acc[0][2] += a.x * b4.z; acc[0][3] += a.x * b4.w;
            acc[1][0] += a.y * b4.x; acc[1][1] += a.y * b4.y; acc[1][2] += a.y * b4.z; acc[1][3] += a.y * b4.w;
            acc[2][0] += a.z * b4.x; acc[2][1] += a.z * b4.y; acc[2][2] += a.z * b4.z; acc[2][3] += a.z * b4.w;
            acc[3][0] += a.w * b4.x; acc[3][1] += a.w * b4.y; acc[3][2] += a.w * b4.z; acc[3][3] += a.w * b4.w;
        }
        __syncthreads();
    }
#pragma unroll
    for (int ii = 0; ii < 4; ++ii) {
        float4 o;
        o.x = acc[ii][0]; o.y = acc[ii][1]; o.z = acc[ii][2]; o.w = acc[ii][3];
        *(float4*)(Y + (size_t)(r0 + ty * 4 + ii) * MM + m0 + tx * 4) = o;
    }
}

// ---------------- fused gather: per-point max/min + channel stats ----------------
__global__ __launch_bounds__(256) void gather_kernel(const float* __restrict__ Y,
                                                     const int* __restrict__ idx,
                                                     double* __restrict__ sums,
                                                     double* __restrict__ sumsq,
                                                     float* __restrict__ xmx,
                                                     float* __restrict__ xmn, int O) {
    __shared__ float us[RCH * 1024];
    __shared__ double red[4][2 * RCH];
    int ob = blockIdx.x * RCH;
    int b = blockIdx.y;
    int nz = blockIdx.z;
    for (int e = threadIdx.x; e < RCH * 1024; e += 256)
        us[e] = Y[(size_t)(ob + (e >> 10)) * MM + b * NN + (e & 1023)];
    __syncthreads();
    float S1[RCH], S2[RCH];
#pragma unroll
    for (int r = 0; r < RCH; ++r) { S1[r] = 0.f; S2[r] = 0.f; }
    for (int p = 0; p < 2; ++p) {
        int n = nz * 512 + p * 256 + threadIdx.x;
        const int* ip = idx + (size_t)(b * NN + n) * KK;
        int qq[20];
#pragma unroll
        for (int w = 0; w < 5; ++w) *(int4*)&qq[w * 4] = ((const int4*)ip)[w];
        float su[RCH], s2l[RCH], mx[RCH], mn[RCH];
#pragma unroll
        for (int r = 0; r < RCH; ++r) { su[r] = 0.f; s2l[r] = 0.f; mx[r] = -INFINITY; mn[r] = INFINITY; }
#pragma unroll
        for (int j = 0; j < KK; ++j) {
            int q = qq[j];
#pragma unroll
            for (int r = 0; r < RCH; ++r) {
                float tv = us[r * 1024 + q];
                su[r] += tv;
                s2l[r] = fmaf(tv, tv, s2l[r]);
                mx[r] = fmaxf(mx[r], tv);
                mn[r] = fminf(mn[r], tv);
            }
        }
#pragma unroll
        for (int r = 0; r < RCH; ++r) {
            float v = Y[(size_t)(O + ob + r) * MM + b * NN + n];
            size_t oi = (size_t)(ob + r) * MM + b * NN + n;
            xmx[oi] = mx[r] + v;
            xmn[oi] = mn[r] + v;
            S1[r] += su[r] + (float)KK * v;
            S2[r] += s2l[r] + 2.f * v * su[r] + (float)KK * v * v;
        }
    }
    int lane = threadIdx.x & 63, wv = threadIdx.x >> 6;
#pragma unroll
    for (int r = 0; r < RCH; ++r) {
        double a = (double)S1[r], c2 = (double)S2[r];
#pragma unroll
        for (int o = 32; o; o >>= 1) {
            a  += __shfl_xor(a, o, 64);
            c2 += __shfl_xor(c2, o, 64);
        }
        if (lane == 0) { red[wv][r] = a; red[wv][RCH + r] = c2; }
    }
    __syncthreads();
    if (threadIdx.x < 2 * RCH) {
        double tt = red[0][threadIdx.x] + red[1][threadIdx.x] + red[2][threadIdx.x] + red[3][threadIdx.x];
        int r = threadIdx.x & (RCH - 1);
        if (threadIdx.x < RCH) atomicAdd(&sums[ob + r], tt);
        else                   atomicAdd(&sumsq[ob + r], tt);
    }
}

// ---------------- bn affine + lrelu, in place on xmx ----------------
__global__ void finalize_kernel(float* __restrict__ xmx, const float* __restrict__ xmn,
                                const double* __restrict__ sums, const double* __restrict__ sumsq,
                                const float* __restrict__ gam, const float* __restrict__ bet) {
    __shared__ float sSC, sBI;
    int o = blockIdx.y;
    if (threadIdx.x == 0) {
        double cnt = (double)BB * NN * KK;
        double mean = sums[o] / cnt;
        double var  = sumsq[o] / cnt - mean * mean;
        double inv  = 1.0 / sqrt(var + 1e-5);
        sSC = (float)((double)gam[o] * inv);
        sBI = (float)((double)bet[o] - mean * (double)gam[o] * inv);
    }
    __syncthreads();
    int m = blockIdx.x * 256 + threadIdx.x;
    size_t i = (size_t)o * MM + m;
    float sc = sSC, bi = sBI;
    float val = (sc >= 0.f) ? xmx[i] : xmn[i];
    float yh = val * sc + bi;
    xmx[i] = fmaxf(yh, 0.2f * yh);
}

// ---------------- fc1 split-K, LDS-staged x4 ----------------
__global__ __launch_bounds__(256) void fc1_partial(const float* __restrict__ x4,
                                                   const float* __restrict__ W,
                                                   float* __restrict__ part) {
    __shared__ float xs[16 * 256];
    int tid = threadIdx.x, lane = tid & 63, wv = tid >> 6;
    int kc = blockIdx.x;                 // 0..63
    int mb = blockIdx.y * 16 + wv * 4;
    float acc[4][16];
#pragma unroll
    for (int i = 0; i < 4; ++i)
#pragma unroll
        for (int j = 0; j < 16; ++j) acc[i][j] = 0.f;
    for (int step = 0; step < 16; ++step) {
        int k0 = kc * 4096 + step * 256;
        int o = k0 >> 10, n0 = k0 & 1023;
        __syncthreads();
#pragma unroll
        for (int it = 0; it < 4; ++it) {
            int e = it * 256 + tid;
            int b16 = e >> 6, l = e & 63;
            *(float4*)&xs[b16 * 256 + l * 4] =
                *(const float4*)(x4 + (size_t)o * MM + b16 * 1024 + n0 + l * 4);
        }
        __syncthreads();
        int kk = k0 + lane * 4;
        float4 w0 = *(const float4*)(W + (size_t)(mb + 0) * KTOT + kk);
        float4 w1 = *(const float4*)(W + (size_t)(mb + 1) * KTOT + kk);
        float4 w2 = *(const float4*)(W + (size_t)(mb + 2) * KTOT + kk);
        float4 w3 = *(const float4*)(W + (size_t)(mb + 3) * KTOT + kk);
#pragma unroll
        for (int b = 0; b < 16; ++b) {
            float4 f = *(const float4*)&xs[b * 256 + lane * 4];
            acc[0][b] += w0.x * f.x + w0.y * f.y + w0.z * f.z + w0.w * f.w;
            acc[1][b] += w1.x * f.x + w1.y * f.y + w1.z * f.z + w1.w * f.w;
            acc[2][b] += w2.x * f.x + w2.y * f.y + w2.z * f.z + w2.w * f.w;
            acc[3][b] += w3.x * f.x + w3.y * f.y + w3.z * f.z + w3.w * f.w;
        }
    }
#pragma unroll
    for (int i = 0; i < 4; ++i)
#pragma unroll
        for (int b = 0; b < 16; ++b) {
            float s = acc[i][b];
#pragma unroll
            for (int o = 32; o; o >>= 1) s += __shfl_xor(s, o, 64);
            if (lane == 0) part[((size_t)kc * 512 + mb + i) * 16 + b] = s;
        }
}

__global__ void fc1_reduce(const float* __restrict__ part, const float* __restrict__ bias,
                           float* __restrict__ x5) {
    int t = blockIdx.x * 256 + threadIdx.x;   // 0..8191
    int m = t & 511, b = t >> 9;
    float s = bias[m];
    for (int kc = 0; kc < SPLIT; ++kc) s += part[((size_t)kc * 512 + m) * 16 + b];
    x5[b * 512 + m] = fmaxf(s, 0.f);
}

__global__ void fc2_kernel(const float* __restrict__ x5, const float* __restrict__ W,
                           const float* __restrict__ bias, float* __restrict__ x6) {
    int t = blockIdx.x * 256 + threadIdx.x;
    int m = t & 511, b = t >> 9;
    const float* wr = W + (size_t)m * 512;
    const float* xr = x5 + b * 512;
    float s = bias[m];
    for (int q = 0; q < 512; q += 4) {
        float4 w = *(const float4*)(wr + q);
        float4 xv = *(const float4*)(xr + q);
        s += w.x * xv.x + w.y * xv.y + w.z * xv.z + w.w * xv.w;
    }
    x6[b * 512 + m] = fmaxf(s, 0.f);
}

__global__ void fc3_kernel(const float* __restrict__ x6, const float* __restrict__ W,
                           const float* __restrict__ bias, float* __restrict__ out) {
    int t = threadIdx.x;
    if (t >= 32) return;
    int b = t >> 1, c = t & 1;
    const float* wr = W + (size_t)c * 512;
    const float* xr = x6 + b * 512;
    float s = bias[c];
    for (int q = 0; q < 512; ++q) s += wr[q] * xr[q];
    out[b * 2 + c] = s;
}

extern "C" void kernel_launch(void* const* d_in, const int* in_sizes, int n_in,
                              void* d_out, int out_size, void* d_ws, size_t ws_size,
                              hipStream_t stream) {
    (void)in_sizes; (void)n_in; (void)out_size; (void)ws_size;
    const float* x = (const float*)d_in[0];
    const float* w_conv[4] = {(const float*)d_in[1], (const float*)d_in[4],
                              (const float*)d_in[7], (const float*)d_in[10]};
    const float* g_bn[4] = {(const float*)d_in[2], (const float*)d_in[5],
                            (const float*)d_in[8], (const float*)d_in[11]};
    const float* b_bn[4] = {(const float*)d_in[3], (const float*)d_in[6],
                            (const float*)d_in[9], (const float*)d_in[12]};
    const float* fc1w = (const float*)d_in[13];
    const float* fc1b = (const float*)d_in[14];
    const float* fc2w = (const float*)d_in[15];
    const float* fc2b = (const float*)d_in[16];
    const float* fc3w = (const float*)d_in[17];
    const float* fc3b = (const float*)d_in[18];
    float* out = (float*)d_out;

    char* wsb = (char*)d_ws;
    size_t off = 0;
    auto alloc = [&](size_t bytes) -> void* {
        void* p = wsb + off;
        off = (off + bytes + 255) & ~(size_t)255;
        return p;
    };
    float* h    = (float*)alloc((size_t)3 * MM * 4);
    float* x1   = (float*)alloc((size_t)64 * MM * 4);
    float* x2   = (float*)alloc((size_t)64 * MM * 4);
    float* x3   = (float*)alloc((size_t)128 * MM * 4);
    float* x4   = (float*)alloc((size_t)256 * MM * 4);
    float* xmn  = (float*)alloc((size_t)256 * MM * 4);
    float* Y    = (float*)alloc((size_t)512 * MM * 4);
    float* G    = (float*)alloc((size_t)BB * NN * NN * 4);
    float* WdT  = (float*)alloc((size_t)512 * 128 * 4);
    int*   idxb = (int*)alloc((size_t)BB * NN * KK * 4);
    float* xxb  = (float*)alloc((size_t)MM * 4);
    double* sums  = (double*)alloc(256 * 8);
    double* sumsq = (double*)alloc(256 * 8);
    float* part = (float*)alloc((size_t)SPLIT * 512 * 16 * 4);
    float* x5   = (float*)alloc((size_t)BB * 512 * 4);
    float* x6   = (float*)alloc((size_t)BB * 512 * 4);

    transpose_h<<<64, 256, 0, stream>>>(x, h);

    struct LayerCfg { const float* xin; int C; int O; float* xout; };
    LayerCfg L[4] = {
        {h, 3, 64, x1}, {x1, 64, 64, x2}, {x2, 64, 128, x3}, {x3, 128, 256, x4}
    };
    for (int l = 0; l < 4; ++l) {
        const float* xin = L[l].xin;
        int C = L[l].C, O = L[l].O;
        float* xout = L[l].xout;
        int R2 = 2 * O;
        xx_kernel<<<64, 256, 0, stream>>>(xin, xxb, C);
        dist_kernel<<<dim3(16, 16, BB), 256, 0, stream>>>(xin, xxb, G, C);
        topk_kernel<<<4096, 256, 0, stream>>>(G, idxb);
        wprep<<<(R2 * C + 255) / 256, 256, 0, stream>>>(w_conv[l], WdT, sums, sumsq, C, O);
        gemm_uv<<<dim3(256, R2 / 64), 256, 0, stream>>>(WdT, xin, Y, C, R2);
        gather_kernel<<<dim3(O / RCH, BB, 2), 256, 0, stream>>>(Y, idxb, sums, sumsq,
                                                                xout, xmn, O);
        finalize_kernel<<<dim3(64, O), 256, 0, stream>>>(xout, xmn, sums, sumsq,
                                                         g_bn[l], b_bn[l]);
    }

    fc1_partial<<<dim3(SPLIT, 32), 256, 0, stream>>>(x4, fc1w, part);
    fc1_reduce<<<32, 256, 0, stream>>>(part, fc1b, x5);
    fc2_kernel<<<32, 256, 0, stream>>>(x5, fc2w, fc2b, x6);
    fc3_kernel<<<1, 64, 0, stream>>>(x6, fc3w, fc3b, out);
}